// Round 1
// baseline (6090.488 us; speedup 1.0000x reference)
//
#include <hip/hip_runtime.h>
#include <math.h>

// Problem constants (fixed by setup_inputs)
#define TLEN   8192
#define CCH    512
#define NBATCH 4

// Conv tiling
#define BT   128   // t-tile
#define BCO  128   // cout-tile
#define BCI  16    // cin chunk

struct Filt { float f[12]; };

// ---------------------------------------------------------------------------
// device helpers
// ---------------------------------------------------------------------------
__device__ __forceinline__ float4 ld4(const float* p) {
  return *reinterpret_cast<const float4*>(p);
}

__device__ __forceinline__ float fast_sin(float x) {
  // sin(x): v_sin_f32 takes revolutions; fract keeps it in valid range for any x
  float r = x * 0.15915494309189535f;
  r -= floorf(r);
  return __builtin_amdgcn_sinf(r);
}

__device__ __forceinline__ float snake1(float u, float a, float rcp) {
  float s = fast_sin(a * u);
  return fmaf(rcp * s, s, u);   // u + (1/a)*sin^2(a*u)
}

// ---------------------------------------------------------------------------
// weight-norm scale: scl[conv][co] = g[co] / ||v[:,:,co]||
// ---------------------------------------------------------------------------
__global__ __launch_bounds__(64)
void scale_k(const float* __restrict__ v1, const float* __restrict__ v2,
             const float* __restrict__ g1, const float* __restrict__ g2,
             float* __restrict__ scl) {
  const int conv = blockIdx.x;                       // 0..5 (0-2: v1, 3-5: v2)
  const int co   = blockIdx.y * 64 + threadIdx.x;    // 0..511
  const float* v = (conv < 3) ? v1 + (size_t)conv * 3 * CCH * CCH
                              : v2 + (size_t)(conv - 3) * 3 * CCH * CCH;
  const float* g = (conv < 3) ? g1 + conv * CCH : g2 + (conv - 3) * CCH;
  float s = 0.f;
  #pragma unroll 8
  for (int j = 0; j < 3 * CCH; ++j) {
    float w = v[(size_t)j * CCH + co];
    s = fmaf(w, w, s);
  }
  scl[conv * CCH + co] = g[co] / sqrtf(s);
}

// ---------------------------------------------------------------------------
// fused Activation1d: 2x upsample -> snake -> 2x downsample
// y[t] = sum_k F[k] * snake(u[clamp(2t+k-5, 0, 2T-1)])
//   even sample u[2t'] = 2*sum_r F[2r]  *x[clamp(t'+r-3)]
//   odd  sample u[2t'+1]=2*sum_r F[2r+1]*x[clamp(t'+r-2)]
// One thread = one (b,t) x 4 channels.
// ---------------------------------------------------------------------------
__global__ __launch_bounds__(256)
void act_k(const float* __restrict__ x, float* __restrict__ y,
           const float* __restrict__ la, Filt F) {
  const int idx = blockIdx.x * 256 + threadIdx.x;    // < NBATCH*TLEN*(CCH/4)
  const int c = (idx & 127) << 2;
  const int t = (idx >> 7) & (TLEN - 1);
  const int b = idx >> 20;
  const float* xb = x + ((size_t)b * TLEN) * CCH + c;

  const float a0 = expf(la[c]),   a1 = expf(la[c+1]);
  const float a2 = expf(la[c+2]), a3 = expf(la[c+3]);
  const float r0 = 1.f/(a0+1e-9f), r1 = 1.f/(a1+1e-9f);
  const float r2 = 1.f/(a2+1e-9f), r3 = 1.f/(a3+1e-9f);

  float acc0=0.f, acc1=0.f, acc2=0.f, acc3=0.f;

  if (t >= 5 && t <= TLEN - 6) {
    // interior: static register window, fully unrolled (no dynamic reg indexing)
    float4 xw[11];
    #pragma unroll
    for (int j = 0; j < 11; ++j) xw[j] = ld4(xb + (size_t)(t - 5 + j) * CCH);
    #pragma unroll
    for (int k = 0; k < 12; ++k) {
      const int b0 = (k & 1) ? ((k - 1) >> 1) : (k >> 1);
      float u0=0.f,u1=0.f,u2=0.f,u3=0.f;
      #pragma unroll
      for (int r = 0; r < 6; ++r) {
        // k even -> odd upsampled sample -> odd taps; k odd -> even taps
        const float tap = (k & 1) ? F.f[2*r] : F.f[2*r+1];
        const float4 xv = xw[b0 + r];
        u0 = fmaf(tap, xv.x, u0); u1 = fmaf(tap, xv.y, u1);
        u2 = fmaf(tap, xv.z, u2); u3 = fmaf(tap, xv.w, u3);
      }
      u0 *= 2.f; u1 *= 2.f; u2 *= 2.f; u3 *= 2.f;
      const float fk = F.f[k];
      acc0 = fmaf(fk, snake1(u0,a0,r0), acc0);
      acc1 = fmaf(fk, snake1(u1,a1,r1), acc1);
      acc2 = fmaf(fk, snake1(u2,a2,r2), acc2);
      acc3 = fmaf(fk, snake1(u3,a3,r3), acc3);
    }
  } else {
    // edge: generic clamped path (few threads)
    for (int k = 0; k < 12; ++k) {
      int m  = 2*t + k - 5;
      int mc = m < 0 ? 0 : (m > 2*TLEN - 1 ? 2*TLEN - 1 : m);
      int tp = mc >> 1;
      int odd = mc & 1;
      float u0=0.f,u1=0.f,u2=0.f,u3=0.f;
      #pragma unroll
      for (int r = 0; r < 6; ++r) {
        int i  = odd ? (tp + r - 2) : (tp + r - 3);
        int ic = i < 0 ? 0 : (i > TLEN - 1 ? TLEN - 1 : i);
        float tap = odd ? F.f[2*r+1] : F.f[2*r];
        float4 xv = ld4(xb + (size_t)ic * CCH);
        u0 = fmaf(tap, xv.x, u0); u1 = fmaf(tap, xv.y, u1);
        u2 = fmaf(tap, xv.z, u2); u3 = fmaf(tap, xv.w, u3);
      }
      u0 *= 2.f; u1 *= 2.f; u2 *= 2.f; u3 *= 2.f;
      const float fk = F.f[k];
      acc0 = fmaf(fk, snake1(u0,a0,r0), acc0);
      acc1 = fmaf(fk, snake1(u1,a1,r1), acc1);
      acc2 = fmaf(fk, snake1(u2,a2,r2), acc2);
      acc3 = fmaf(fk, snake1(u3,a3,r3), acc3);
    }
  }
  float4 o; o.x = acc0; o.y = acc1; o.z = acc2; o.w = acc3;
  *reinterpret_cast<float4*>(y + ((size_t)b * TLEN + t) * CCH + c) = o;
}

// ---------------------------------------------------------------------------
// weight-normed dilated conv, K=3, SAME (zero) padding, fused scale/bias/residual
// y[b,t,co] = scl[co] * sum_{k,ci} v[k,ci,co]*x[b,t+(k-1)*DIL,ci] + bia[co] (+res)
// 256 threads; tile 128t x 128co; 8x8 outputs/thread; 16-ci chunks.
// Shifts are baked into the 3 staged input copies so compute indexing is uniform.
// ---------------------------------------------------------------------------
template<int DIL>
__global__ __launch_bounds__(256)
void conv_k(const float* __restrict__ xin, const float* __restrict__ v,
            const float* __restrict__ scl, const float* __restrict__ bia,
            const float* __restrict__ res, float* __restrict__ out) {
  __shared__ float xs[3][BCI][BT + 4];   // +4 pad: breaks write conflicts, keeps 16B align
  __shared__ float wsh[3][BCI][BCO];

  const int tid = threadIdx.x;
  const int tx = tid & 15, ty = tid >> 4;
  const int b  = blockIdx.x / (TLEN / BT);
  const int t0 = (blockIdx.x % (TLEN / BT)) * BT;
  const int co0 = blockIdx.y * BCO;
  const float* xb = xin + (size_t)b * TLEN * CCH;

  float acc[8][8];
  #pragma unroll
  for (int r = 0; r < 8; ++r)
    #pragma unroll
    for (int j = 0; j < 8; ++j) acc[r][j] = 0.f;

  for (int ci0 = 0; ci0 < CCH; ci0 += BCI) {
    __syncthreads();
    // stage x: 3 shifted copies, xs[k][ci][j] = x[t0 + j + (k-1)*DIL, ci0+ci] (0 outside)
    #pragma unroll
    for (int n = 0; n < (3 * BCI * BT) / 256; ++n) {
      int idx = tid + n * 256;
      int ci = idx & 15;
      int j  = (idx >> 4) & 127;
      int k  = idx >> 11;
      int t  = t0 + j + (k - 1) * DIL;
      float val = (t >= 0 && t < TLEN) ? xb[(size_t)t * CCH + ci0 + ci] : 0.f;
      xs[k][ci][j] = val;
    }
    // stage w: wsh[k][ci][co] = v[k, ci0+ci, co0+co]
    #pragma unroll
    for (int n = 0; n < (3 * BCI * BCO) / 256; ++n) {
      int idx = tid + n * 256;
      int co = idx & 127;
      int ci = (idx >> 7) & 15;
      int k  = idx >> 11;
      wsh[k][ci][co] = v[((size_t)k * CCH + ci0 + ci) * CCH + co0 + co];
    }
    __syncthreads();

    #pragma unroll
    for (int ci = 0; ci < BCI; ++ci) {
      #pragma unroll
      for (int k = 0; k < 3; ++k) {
        const float4 bA = ld4(&wsh[k][ci][tx * 4]);
        const float4 bB = ld4(&wsh[k][ci][64 + tx * 4]);
        const float4 a0 = ld4(&xs[k][ci][ty * 8]);
        const float4 a1 = ld4(&xs[k][ci][ty * 8 + 4]);
        const float av[8] = {a0.x, a0.y, a0.z, a0.w, a1.x, a1.y, a1.z, a1.w};
        #pragma unroll
        for (int r = 0; r < 8; ++r) {
          acc[r][0] = fmaf(av[r], bA.x, acc[r][0]);
          acc[r][1] = fmaf(av[r], bA.y, acc[r][1]);
          acc[r][2] = fmaf(av[r], bA.z, acc[r][2]);
          acc[r][3] = fmaf(av[r], bA.w, acc[r][3]);
          acc[r][4] = fmaf(av[r], bB.x, acc[r][4]);
          acc[r][5] = fmaf(av[r], bB.y, acc[r][5]);
          acc[r][6] = fmaf(av[r], bB.z, acc[r][6]);
          acc[r][7] = fmaf(av[r], bB.w, acc[r][7]);
        }
      }
    }
  }

  // epilogue: scale, bias, optional residual
  const int coA = co0 + tx * 4;
  const int coB = coA + 64;
  const float4 sA = ld4(&scl[coA]);  const float4 sB = ld4(&scl[coB]);
  const float4 bA = ld4(&bia[coA]);  const float4 bB = ld4(&bia[coB]);
  #pragma unroll
  for (int r = 0; r < 8; ++r) {
    const int t = t0 + ty * 8 + r;
    const size_t row = ((size_t)b * TLEN + t) * CCH;
    float4 oA, oB;
    oA.x = fmaf(acc[r][0], sA.x, bA.x); oA.y = fmaf(acc[r][1], sA.y, bA.y);
    oA.z = fmaf(acc[r][2], sA.z, bA.z); oA.w = fmaf(acc[r][3], sA.w, bA.w);
    oB.x = fmaf(acc[r][4], sB.x, bB.x); oB.y = fmaf(acc[r][5], sB.y, bB.y);
    oB.z = fmaf(acc[r][6], sB.z, bB.z); oB.w = fmaf(acc[r][7], sB.w, bB.w);
    if (res) {
      const float4 rA = ld4(res + row + coA);
      const float4 rB = ld4(res + row + coB);
      oA.x += rA.x; oA.y += rA.y; oA.z += rA.z; oA.w += rA.w;
      oB.x += rB.x; oB.y += rB.y; oB.z += rB.z; oB.w += rB.w;
    }
    *reinterpret_cast<float4*>(out + row + coA) = oA;
    *reinterpret_cast<float4*>(out + row + coB) = oB;
  }
}

// ---------------------------------------------------------------------------
// host: kaiser-sinc filter (double precision, matches numpy)
// ---------------------------------------------------------------------------
static double bessel_i0(double x) {
  double t = 1.0, s = 1.0, q = x * x * 0.25;
  for (int k = 1; k < 64; ++k) {
    t *= q / ((double)k * (double)k);
    s += t;
    if (t < 1e-18 * s) break;
  }
  return s;
}

static void make_filter(Filt* F) {
  const double cutoff = 0.25, hw = 0.3;   // 0.5/RATIO, 0.6/RATIO
  const int ks = 12, half = 6;
  const double A = 2.285 * (half - 1) * M_PI * (4.0 * hw) + 7.95;
  double beta;
  if (A > 50.0)      beta = 0.1102 * (A - 8.7);
  else if (A >= 21.0) beta = 0.5842 * pow(A - 21.0, 0.4) + 0.07886 * (A - 21.0);
  else               beta = 0.0;
  const double i0b = bessel_i0(beta);
  double f[12], sum = 0.0;
  for (int n = 0; n < 12; ++n) {
    double rr = 2.0 * n / (ks - 1) - 1.0;
    double w  = bessel_i0(beta * sqrt(fmax(0.0, 1.0 - rr * rr))) / i0b;
    double tm = (double)(n - half) + 0.5;
    double sx = 2.0 * cutoff * tm;
    double snc = (sx == 0.0) ? 1.0 : sin(M_PI * sx) / (M_PI * sx);
    f[n] = 2.0 * cutoff * w * snc;
    sum += f[n];
  }
  for (int n = 0; n < 12; ++n) F->f[n] = (float)(f[n] / sum);
}

// ---------------------------------------------------------------------------
extern "C" void kernel_launch(void* const* d_in, const int* in_sizes, int n_in,
                              void* d_out, int out_size, void* d_ws, size_t ws_size,
                              hipStream_t stream) {
  (void)in_sizes; (void)n_in; (void)out_size; (void)ws_size;
  const float* x  = (const float*)d_in[0];
  const float* v1 = (const float*)d_in[1];
  const float* g1 = (const float*)d_in[2];
  const float* b1 = (const float*)d_in[3];
  const float* v2 = (const float*)d_in[4];
  const float* g2 = (const float*)d_in[5];
  const float* b2 = (const float*)d_in[6];
  const float* al = (const float*)d_in[7];
  float* out = (float*)d_out;

  const size_t N = (size_t)NBATCH * TLEN * CCH;
  // ws layout: [w0: N floats][w1: N floats][scales: 6*512]  (~128.2 MiB)
  float* w0  = (float*)d_ws;
  float* w1  = w0 + N;
  float* scl = w1 + N;

  Filt F;
  make_filter(&F);

  scale_k<<<dim3(6, 8), 64, 0, stream>>>(v1, v2, g1, g2, scl);

  const dim3 cgrid(NBATCH * TLEN / BT, CCH / BCO);
  const int dil[3] = {1, 3, 5};
  const int nblk_act = (NBATCH * TLEN * (CCH / 4)) / 256;

  for (int i = 0; i < 3; ++i) {
    const float* xsrc = (i == 0) ? x : out;  // running residual lives in d_out
    // act1d #1
    act_k<<<nblk_act, 256, 0, stream>>>(xsrc, w0, al + (size_t)(2 * i) * CCH, F);
    // conv1 (dilated)
    const float* vv1 = v1 + (size_t)i * 3 * CCH * CCH;
    if (dil[i] == 1)
      conv_k<1><<<cgrid, 256, 0, stream>>>(w0, vv1, scl + i * CCH, b1 + i * CCH, nullptr, w1);
    else if (dil[i] == 3)
      conv_k<3><<<cgrid, 256, 0, stream>>>(w0, vv1, scl + i * CCH, b1 + i * CCH, nullptr, w1);
    else
      conv_k<5><<<cgrid, 256, 0, stream>>>(w0, vv1, scl + i * CCH, b1 + i * CCH, nullptr, w1);
    // act1d #2
    act_k<<<nblk_act, 256, 0, stream>>>(w1, w0, al + (size_t)(2 * i + 1) * CCH, F);
    // conv2 (dil=1) + residual; output becomes the new running x (in d_out)
    conv_k<1><<<cgrid, 256, 0, stream>>>(w0, v2 + (size_t)i * 3 * CCH * CCH,
                                         scl + (3 + i) * CCH, b2 + i * CCH, xsrc, out);
  }
}

// Round 2
// 1069.357 us; speedup vs baseline: 5.6955x; 5.6955x over previous
//
#include <hip/hip_runtime.h>
#include <math.h>

// Problem constants (fixed by setup_inputs)
#define TLEN   8192
#define CCH    512
#define NBATCH 4
#define GUARD  8
#define XROWS  (TLEN + 2 * GUARD)   // 8208 guarded rows per batch (zero pad for taps)

typedef __attribute__((ext_vector_type(8))) short short8;
typedef __attribute__((ext_vector_type(4))) float f32x4;

struct Filt { float f[12]; };

#define MFMA16(a, b, c) __builtin_amdgcn_mfma_f32_16x16x32_bf16(a, b, c, 0, 0, 0)

// ---------------------------------------------------------------------------
// device helpers
// ---------------------------------------------------------------------------
__device__ __forceinline__ float4 ld4(const float* p) {
  return *reinterpret_cast<const float4*>(p);
}

__device__ __forceinline__ unsigned short f2bf(float f) {
  unsigned u = __float_as_uint(f);
  unsigned r = (u + 0x7fffu + ((u >> 16) & 1u)) >> 16;   // RNE
  return (unsigned short)r;
}

__device__ __forceinline__ float fast_sin(float x) {
  float r = x * 0.15915494309189535f;   // radians -> revolutions
  r -= floorf(r);
  return __builtin_amdgcn_sinf(r);
}

__device__ __forceinline__ float snake1(float u, float a, float rcp) {
  float s = fast_sin(a * u);
  return fmaf(rcp * s, s, u);   // u + (1/a)*sin^2(a*u)
}

// global (per-lane addr) -> LDS (wave-uniform base; HW adds lane*16), 16B/lane
__device__ __forceinline__ void gload16(const void* g, void* l) {
  __builtin_amdgcn_global_load_lds(
      (const __attribute__((address_space(1))) unsigned int*)g,
      (__attribute__((address_space(3))) unsigned int*)l, 16, 0, 0);
}

// ---------------------------------------------------------------------------
// weight-norm scale: scl[conv][co] = g[co] / ||v[:,:,co]||
// ---------------------------------------------------------------------------
__global__ __launch_bounds__(64)
void scale_k(const float* __restrict__ v1, const float* __restrict__ v2,
             const float* __restrict__ g1, const float* __restrict__ g2,
             float* __restrict__ scl) {
  const int conv = blockIdx.x;                       // 0..5 (0-2: v1, 3-5: v2)
  const int co   = blockIdx.y * 64 + threadIdx.x;    // 0..511
  const float* v = (conv < 3) ? v1 + (size_t)conv * 3 * CCH * CCH
                              : v2 + (size_t)(conv - 3) * 3 * CCH * CCH;
  const float* g = (conv < 3) ? g1 + conv * CCH : g2 + (conv - 3) * CCH;
  float s = 0.f;
  #pragma unroll 8
  for (int j = 0; j < 3 * CCH; ++j) {
    float w = v[(size_t)j * CCH + co];
    s = fmaf(w, w, s);
  }
  scl[conv * CCH + co] = g[co] / sqrtf(s);
}

// ---------------------------------------------------------------------------
// zero the guard rows of the bf16 activation buffer
// ---------------------------------------------------------------------------
__global__ __launch_bounds__(256)
void zguard_k(unsigned short* __restrict__ xb) {
  const int tid = blockIdx.x * 256 + threadIdx.x;    // 4*16*512 = 32768 total
  const int cc = tid & 511;
  const int g  = (tid >> 9) & 15;
  const int b  = tid >> 13;
  const int row = (g < 8) ? g : (TLEN + g);          // 0..7 and 8200..8207
  xb[((size_t)b * XROWS + row) * CCH + cc] = 0;
}

// ---------------------------------------------------------------------------
// pack weights into MFMA B-fragment order (weight-norm scale folded in).
// wp[c][tap][cib][cob][cb][lane][j]  (bf16), where
//   cb = nf*2 + kk, co = cob*128 + nf*16 + (lane&15),
//   ci = cib*64 + kk*32 + (lane>>4)*8 + j
// One wave per 512-element chunk -> write = contiguous 16B/lane.
// ---------------------------------------------------------------------------
__global__ __launch_bounds__(256)
void wprep_k(const float* __restrict__ v1, const float* __restrict__ v2,
             const float* __restrict__ scl, unsigned short* __restrict__ wp) {
  const int gtid = blockIdx.x * 256 + threadIdx.x;
  const int lane = gtid & 63;
  const int gw = gtid >> 6;            // 0..9215
  const int c  = gw / 1536;
  int r = gw - c * 1536;
  const int tap = r >> 9;  r &= 511;
  const int cib = r >> 6;  r &= 63;
  const int cob = r >> 4;
  const int cb  = r & 15;
  const int nf = cb >> 1, kk = cb & 1;
  const int co  = cob * 128 + nf * 16 + (lane & 15);
  const int ci0 = cib * 64 + kk * 32 + (lane >> 4) * 8;
  const float* v = (c < 3) ? v1 + (size_t)c * 3 * CCH * CCH
                           : v2 + (size_t)(c - 3) * 3 * CCH * CCH;
  const float s = scl[c * CCH + co];
  unsigned short o[8];
  #pragma unroll
  for (int j = 0; j < 8; ++j) {
    float w = v[((size_t)tap * CCH + ci0 + j) * CCH + co] * s;
    o[j] = f2bf(w);
  }
  *reinterpret_cast<short8*>(wp + (size_t)gw * 512 + lane * 8) =
      *reinterpret_cast<const short8*>(o);
}

// ---------------------------------------------------------------------------
// fused Activation1d: 2x upsample -> snake -> 2x downsample. Output bf16 into
// the guarded buffer (guard rows stay zero).
// ---------------------------------------------------------------------------
__global__ __launch_bounds__(256)
void act_k(const float* __restrict__ x, unsigned short* __restrict__ y,
           const float* __restrict__ la, Filt F) {
  const int idx = blockIdx.x * 256 + threadIdx.x;    // < NBATCH*TLEN*(CCH/4)
  const int c = (idx & 127) << 2;
  const int t = (idx >> 7) & (TLEN - 1);
  const int b = idx >> 20;
  const float* xbp = x + ((size_t)b * TLEN) * CCH + c;

  const float a0 = expf(la[c]),   a1 = expf(la[c+1]);
  const float a2 = expf(la[c+2]), a3 = expf(la[c+3]);
  const float r0 = 1.f/(a0+1e-9f), r1 = 1.f/(a1+1e-9f);
  const float r2 = 1.f/(a2+1e-9f), r3 = 1.f/(a3+1e-9f);

  float acc0=0.f, acc1=0.f, acc2=0.f, acc3=0.f;

  if (t >= 5 && t <= TLEN - 6) {
    float4 xw[11];
    #pragma unroll
    for (int j = 0; j < 11; ++j) xw[j] = ld4(xbp + (size_t)(t - 5 + j) * CCH);
    #pragma unroll
    for (int k = 0; k < 12; ++k) {
      const int b0 = (k & 1) ? ((k - 1) >> 1) : (k >> 1);
      float u0=0.f,u1=0.f,u2=0.f,u3=0.f;
      #pragma unroll
      for (int r = 0; r < 6; ++r) {
        const float tap = (k & 1) ? F.f[2*r] : F.f[2*r+1];
        const float4 xv = xw[b0 + r];
        u0 = fmaf(tap, xv.x, u0); u1 = fmaf(tap, xv.y, u1);
        u2 = fmaf(tap, xv.z, u2); u3 = fmaf(tap, xv.w, u3);
      }
      u0 *= 2.f; u1 *= 2.f; u2 *= 2.f; u3 *= 2.f;
      const float fk = F.f[k];
      acc0 = fmaf(fk, snake1(u0,a0,r0), acc0);
      acc1 = fmaf(fk, snake1(u1,a1,r1), acc1);
      acc2 = fmaf(fk, snake1(u2,a2,r2), acc2);
      acc3 = fmaf(fk, snake1(u3,a3,r3), acc3);
    }
  } else {
    for (int k = 0; k < 12; ++k) {
      int m  = 2*t + k - 5;
      int mc = m < 0 ? 0 : (m > 2*TLEN - 1 ? 2*TLEN - 1 : m);
      int tp = mc >> 1;
      int odd = mc & 1;
      float u0=0.f,u1=0.f,u2=0.f,u3=0.f;
      #pragma unroll
      for (int r = 0; r < 6; ++r) {
        int i  = odd ? (tp + r - 2) : (tp + r - 3);
        int ic = i < 0 ? 0 : (i > TLEN - 1 ? TLEN - 1 : i);
        float tap = odd ? F.f[2*r+1] : F.f[2*r];
        float4 xv = ld4(xbp + (size_t)ic * CCH);
        u0 = fmaf(tap, xv.x, u0); u1 = fmaf(tap, xv.y, u1);
        u2 = fmaf(tap, xv.z, u2); u3 = fmaf(tap, xv.w, u3);
      }
      u0 *= 2.f; u1 *= 2.f; u2 *= 2.f; u3 *= 2.f;
      const float fk = F.f[k];
      acc0 = fmaf(fk, snake1(u0,a0,r0), acc0);
      acc1 = fmaf(fk, snake1(u1,a1,r1), acc1);
      acc2 = fmaf(fk, snake1(u2,a2,r2), acc2);
      acc3 = fmaf(fk, snake1(u3,a3,r3), acc3);
    }
  }
  ushort4 o;
  o.x = f2bf(acc0); o.y = f2bf(acc1); o.z = f2bf(acc2); o.w = f2bf(acc3);
  *reinterpret_cast<ushort4*>(y + ((size_t)b * XROWS + GUARD + t) * CCH + c) = o;
}

// ---------------------------------------------------------------------------
// MFMA conv: out[b,t,co] = sum_{tap,ci} wp[tap,ci,co]*xb[t+(tap-1)*DIL, ci]
//            (+ bias, + optional residual).  GEMM M=32768, N=512, K=1536.
// 128x128 tile, 4 waves, 64x64/wave, 16x16x32 bf16 MFMA.
// Staging: global_load_lds 16B/lane; A gathered fragment-order via per-lane
// global addresses (guarded rows -> no bounds checks); B pre-packed linear.
// ---------------------------------------------------------------------------
template<int DIL>
__global__ __launch_bounds__(256)
void convm_k(const unsigned short* __restrict__ xb,
             const unsigned short* __restrict__ wp,
             const float* __restrict__ bia,
             const float* __restrict__ res,
             float* __restrict__ out) {
  __shared__ unsigned short As[16 * 512];   // 16 chunks: ab = mf*2+kk
  __shared__ unsigned short Bs[16 * 512];   // 16 chunks: cb = nf*2+kk

  const int tid  = threadIdx.x;
  const int lane = tid & 63;
  const int wid  = tid >> 6;
  const int wr = wid >> 1, wc = wid & 1;
  const int tb = blockIdx.x;               // 0..255
  const int b  = tb >> 6;
  const int t0 = (tb & 63) * 128;
  const int co0 = blockIdx.y * 128;

  const int lrow = lane & 15;
  const int lk8  = (lane >> 4) * 8;

  f32x4 acc[4][4] = {};

  // per-lane A base: row (t0 + lrow) of this batch (guarded), ci offset lk8
  const unsigned short* xbase =
      xb + ((size_t)b * XROWS + GUARD + t0 + lrow) * CCH + lk8;

  for (int tap = 0; tap < 3; ++tap) {
    const int shift = (tap - 1) * DIL;
    const unsigned short* xg = xbase + (ptrdiff_t)shift * CCH;
    for (int cib = 0; cib < 8; ++cib) {
      __syncthreads();
      // stage A: 4 chunks per wave (ab = wid*4+u; mf=ab>>1, kk=ab&1)
      #pragma unroll
      for (int u = 0; u < 4; ++u) {
        const int ab = wid * 4 + u;
        const int mf = ab >> 1, kk = ab & 1;
        const unsigned short* g = xg + (size_t)(mf * 16) * CCH + cib * 64 + kk * 32;
        gload16(g, &As[ab * 512]);
      }
      // stage B: pre-packed, fully linear
      #pragma unroll
      for (int u = 0; u < 4; ++u) {
        const int cb = wid * 4 + u;
        const unsigned short* g =
            wp + ((((size_t)(tap * 8 + cib) * 4 + blockIdx.y) * 16 + cb) * 512) + lane * 8;
        gload16(g, &Bs[cb * 512]);
      }
      __syncthreads();
      #pragma unroll
      for (int kk = 0; kk < 2; ++kk) {
        short8 af[4], bf[4];
        #pragma unroll
        for (int i = 0; i < 4; ++i)
          af[i] = *reinterpret_cast<const short8*>(&As[((wr * 4 + i) * 2 + kk) * 512 + lane * 8]);
        #pragma unroll
        for (int j = 0; j < 4; ++j)
          bf[j] = *reinterpret_cast<const short8*>(&Bs[((wc * 4 + j) * 2 + kk) * 512 + lane * 8]);
        #pragma unroll
        for (int i = 0; i < 4; ++i)
          #pragma unroll
          for (int j = 0; j < 4; ++j)
            acc[i][j] = MFMA16(af[i], bf[j], acc[i][j]);
      }
    }
  }

  // epilogue: D row = (lane>>4)*4+q, col = lane&15
  #pragma unroll
  for (int j = 0; j < 4; ++j) {
    const int co = co0 + (wc * 4 + j) * 16 + lrow;
    const float bv = bia[co];
    #pragma unroll
    for (int i = 0; i < 4; ++i) {
      const int t = t0 + (wr * 4 + i) * 16 + (lane >> 4) * 4;
      #pragma unroll
      for (int q = 0; q < 4; ++q) {
        const size_t off = ((size_t)b * TLEN + t + q) * CCH + co;
        float o = acc[i][j][q] + bv;
        if (res) o += res[off];
        out[off] = o;
      }
    }
  }
}

// ---------------------------------------------------------------------------
// host: kaiser-sinc filter (double precision, matches numpy)
// ---------------------------------------------------------------------------
static double bessel_i0(double x) {
  double t = 1.0, s = 1.0, q = x * x * 0.25;
  for (int k = 1; k < 64; ++k) {
    t *= q / ((double)k * (double)k);
    s += t;
    if (t < 1e-18 * s) break;
  }
  return s;
}

static void make_filter(Filt* F) {
  const double cutoff = 0.25, hw = 0.3;
  const int ks = 12, half = 6;
  const double A = 2.285 * (half - 1) * M_PI * (4.0 * hw) + 7.95;
  double beta;
  if (A > 50.0)       beta = 0.1102 * (A - 8.7);
  else if (A >= 21.0) beta = 0.5842 * pow(A - 21.0, 0.4) + 0.07886 * (A - 21.0);
  else                beta = 0.0;
  const double i0b = bessel_i0(beta);
  double f[12], sum = 0.0;
  for (int n = 0; n < 12; ++n) {
    double rr = 2.0 * n / (ks - 1) - 1.0;
    double w  = bessel_i0(beta * sqrt(fmax(0.0, 1.0 - rr * rr))) / i0b;
    double tm = (double)(n - half) + 0.5;
    double sx = 2.0 * cutoff * tm;
    double snc = (sx == 0.0) ? 1.0 : sin(M_PI * sx) / (M_PI * sx);
    f[n] = 2.0 * cutoff * w * snc;
    sum += f[n];
  }
  for (int n = 0; n < 12; ++n) F->f[n] = (float)(f[n] / sum);
}

// ---------------------------------------------------------------------------
extern "C" void kernel_launch(void* const* d_in, const int* in_sizes, int n_in,
                              void* d_out, int out_size, void* d_ws, size_t ws_size,
                              hipStream_t stream) {
  (void)in_sizes; (void)n_in; (void)out_size; (void)ws_size;
  const float* x  = (const float*)d_in[0];
  const float* v1 = (const float*)d_in[1];
  const float* g1 = (const float*)d_in[2];
  const float* b1 = (const float*)d_in[3];
  const float* v2 = (const float*)d_in[4];
  const float* g2 = (const float*)d_in[5];
  const float* b2 = (const float*)d_in[6];
  const float* al = (const float*)d_in[7];
  float* out = (float*)d_out;

  const size_t N = (size_t)NBATCH * TLEN * CCH;
  // ws: [w1 fp32: N][xb bf16 guarded][wp bf16 packed][scl] ~ 107 MB
  float* w1 = (float*)d_ws;
  unsigned short* xbuf = (unsigned short*)(w1 + N);
  unsigned short* wp   = xbuf + (size_t)NBATCH * XROWS * CCH;
  float* scl = (float*)(wp + (size_t)6 * 3 * CCH * CCH);

  Filt F;
  make_filter(&F);

  zguard_k<<<128, 256, 0, stream>>>(xbuf);
  scale_k<<<dim3(6, 8), 64, 0, stream>>>(v1, v2, g1, g2, scl);
  wprep_k<<<2304, 256, 0, stream>>>(v1, v2, scl, wp);

  const dim3 cgrid(NBATCH * TLEN / 128, 4);
  const int nblk_act = (NBATCH * TLEN * (CCH / 4)) / 256;
  const size_t wsz = (size_t)3 * CCH * CCH;

  for (int i = 0; i < 3; ++i) {
    const float* xsrc = (i == 0) ? x : out;   // running residual lives in d_out
    // act1d #1 -> xb (bf16)
    act_k<<<nblk_act, 256, 0, stream>>>(xsrc, xbuf, al + (size_t)(2 * i) * CCH, F);
    // conv1 (dilated) -> w1 (fp32)
    if (i == 0)
      convm_k<1><<<cgrid, 256, 0, stream>>>(xbuf, wp + 0 * wsz, b1 + 0 * CCH, nullptr, w1);
    else if (i == 1)
      convm_k<3><<<cgrid, 256, 0, stream>>>(xbuf, wp + 1 * wsz, b1 + 1 * CCH, nullptr, w1);
    else
      convm_k<5><<<cgrid, 256, 0, stream>>>(xbuf, wp + 2 * wsz, b1 + 2 * CCH, nullptr, w1);
    // act1d #2 -> xb (bf16)
    act_k<<<nblk_act, 256, 0, stream>>>(w1, xbuf, al + (size_t)(2 * i + 1) * CCH, F);
    // conv2 (dil=1) + residual -> out
    convm_k<1><<<cgrid, 256, 0, stream>>>(xbuf, wp + (3 + i) * wsz, b2 + i * CCH, xsrc, out);
  }
}

// Round 3
// 798.718 us; speedup vs baseline: 7.6253x; 1.3388x over previous
//
#include <hip/hip_runtime.h>
#include <math.h>

// Problem constants (fixed by setup_inputs)
#define TLEN   8192
#define CCH    512
#define NBATCH 4
#define GUARD_B 8
#define GUARD_T 16
#define XROWS  (TLEN + GUARD_B + GUARD_T)   // 8216 guarded rows per batch

typedef __attribute__((ext_vector_type(8))) short short8;
typedef __attribute__((ext_vector_type(4))) float f32x4;

struct Filt { float f[12]; };

#define MFMA16(a, b, c) __builtin_amdgcn_mfma_f32_16x16x32_bf16(a, b, c, 0, 0, 0)

// ---------------------------------------------------------------------------
// device helpers
// ---------------------------------------------------------------------------
__device__ __forceinline__ unsigned short f2bf(float f) {
  unsigned u = __float_as_uint(f);
  unsigned r = (u + 0x7fffu + ((u >> 16) & 1u)) >> 16;   // RNE
  return (unsigned short)r;
}

__device__ __forceinline__ float fast_sin(float x) {
  float r = x * 0.15915494309189535f;   // radians -> revolutions
  r -= floorf(r);
  return __builtin_amdgcn_sinf(r);
}

__device__ __forceinline__ float snake1(float u, float a, float rcp) {
  float s = fast_sin(a * u);
  return fmaf(rcp * s, s, u);   // u + (1/a)*sin^2(a*u)
}

// global (per-lane addr) -> LDS (wave-uniform base; HW adds lane*16), 16B/lane
__device__ __forceinline__ void gload16(const void* g, void* l) {
  __builtin_amdgcn_global_load_lds(
      (const __attribute__((address_space(1))) unsigned int*)g,
      (__attribute__((address_space(3))) unsigned int*)l, 16, 0, 0);
}

// ---------------------------------------------------------------------------
// weight-norm scale: scl[conv][co] = g[co] / ||v[:,:,co]||
// ---------------------------------------------------------------------------
__global__ __launch_bounds__(64)
void scale_k(const float* __restrict__ v1, const float* __restrict__ v2,
             const float* __restrict__ g1, const float* __restrict__ g2,
             float* __restrict__ scl) {
  const int conv = blockIdx.x;                       // 0..5 (0-2: v1, 3-5: v2)
  const int co   = blockIdx.y * 64 + threadIdx.x;    // 0..511
  const float* v = (conv < 3) ? v1 + (size_t)conv * 3 * CCH * CCH
                              : v2 + (size_t)(conv - 3) * 3 * CCH * CCH;
  const float* g = (conv < 3) ? g1 + conv * CCH : g2 + (conv - 3) * CCH;
  float s = 0.f;
  #pragma unroll 8
  for (int j = 0; j < 3 * CCH; ++j) {
    float w = v[(size_t)j * CCH + co];
    s = fmaf(w, w, s);
  }
  scl[conv * CCH + co] = g[co] / sqrtf(s);
}

// ---------------------------------------------------------------------------
// zero the guard rows of the bf16 activation buffer (24 rows per batch)
// grid: 96 blocks x 512 threads
// ---------------------------------------------------------------------------
__global__ __launch_bounds__(512)
void zguard_k(unsigned short* __restrict__ xb) {
  const int b = blockIdx.x / 24;
  const int g = blockIdx.x % 24;
  const int row = (g < 8) ? g : (TLEN + g);          // 0..7 and 8200..8215
  xb[((size_t)b * XROWS + row) * CCH + threadIdx.x] = 0;
}

// ---------------------------------------------------------------------------
// pack weights into MFMA B-fragment order (weight-norm scale folded in).
// wp[c][tap][cib][cob][cb][lane][j]  (bf16), where
//   cb = nf*2 + kk, co = cob*128 + nf*16 + (lane&15),
//   ci = cib*64 + kk*32 + (lane>>4)*8 + j
// ---------------------------------------------------------------------------
__global__ __launch_bounds__(256)
void wprep_k(const float* __restrict__ v1, const float* __restrict__ v2,
             const float* __restrict__ scl, unsigned short* __restrict__ wp) {
  const int gtid = blockIdx.x * 256 + threadIdx.x;
  const int lane = gtid & 63;
  const int gw = gtid >> 6;            // 0..9215
  const int c  = gw / 1536;
  int r = gw - c * 1536;
  const int tap = r >> 9;  r &= 511;
  const int cib = r >> 6;  r &= 63;
  const int cob = r >> 4;
  const int cb  = r & 15;
  const int nf = cb >> 1, kk = cb & 1;
  const int co  = cob * 128 + nf * 16 + (lane & 15);
  const int ci0 = cib * 64 + kk * 32 + (lane >> 4) * 8;
  const float* v = (c < 3) ? v1 + (size_t)c * 3 * CCH * CCH
                           : v2 + (size_t)(c - 3) * 3 * CCH * CCH;
  const float s = scl[c * CCH + co];
  unsigned short o[8];
  #pragma unroll
  for (int j = 0; j < 8; ++j) {
    float w = v[((size_t)tap * CCH + ci0 + j) * CCH + co] * s;
    o[j] = f2bf(w);
  }
  *reinterpret_cast<short8*>(wp + (size_t)gw * 512 + lane * 8) =
      *reinterpret_cast<const short8*>(o);
}

// ---------------------------------------------------------------------------
// fused Activation1d: 2x upsample -> snake -> 2x downsample, strip-tiled.
// Each thread: 4 consecutive t outputs x 4 channels. Upsampled samples
// s[m] = snake(u[m]) computed ONCE (18 per strip) then 12-tap downsample.
//   y[t0+tt] = sum_k F[k] * s[2tt+k],  s indices mi=0..17, m_abs=2*t0-5+mi
//   mi odd  (m_abs even): u = 2*sum_r F[2r]  * xw[(mi-5)/2 + r + 2]
//   mi even (m_abs odd) : u = 2*sum_r F[2r+1]* xw[(mi-6)/2 + r + 3]
//   xw[j] = x[t0-5+j], j in [0,13]
// ---------------------------------------------------------------------------
__global__ __launch_bounds__(256)
void act_k(const float* __restrict__ x, unsigned short* __restrict__ y,
           const float* __restrict__ la, Filt F) {
  const int idx = blockIdx.x * 256 + threadIdx.x;    // 4 * 2048 * 128 threads
  const int c  = (idx & 127) << 2;
  const int ts = (idx >> 7) & 2047;                  // strip index (t0 = 4*ts)
  const int b  = idx >> 18;
  const int t0 = ts * 4;
  const float* xbp = x + ((size_t)b * TLEN) * CCH + c;

  float av[4], rv[4];
  #pragma unroll
  for (int ch = 0; ch < 4; ++ch) {
    av[ch] = expf(la[c + ch]);
    rv[ch] = 1.f / (av[ch] + 1e-9f);
  }

  float acc[4][4];   // [tt][ch]

  if (ts >= 2 && ts <= 2045) {
    f32x4 xw[14];
    const float* xp = xbp + (size_t)(t0 - 5) * CCH;
    #pragma unroll
    for (int j = 0; j < 14; ++j)
      xw[j] = *reinterpret_cast<const f32x4*>(xp + (size_t)j * CCH);

    #pragma unroll
    for (int ch = 0; ch < 4; ++ch) {
      float s[18];
      #pragma unroll
      for (int mi = 0; mi < 18; ++mi) {
        float u = 0.f;
        if (mi & 1) {
          const int base = (mi - 5) / 2 + 2;
          #pragma unroll
          for (int r = 0; r < 6; ++r) u = fmaf(F.f[2*r], xw[base + r][ch], u);
        } else {
          const int base = (mi - 6) / 2 + 3;
          #pragma unroll
          for (int r = 0; r < 6; ++r) u = fmaf(F.f[2*r+1], xw[base + r][ch], u);
        }
        u *= 2.f;
        s[mi] = snake1(u, av[ch], rv[ch]);
      }
      #pragma unroll
      for (int tt = 0; tt < 4; ++tt) {
        float a = 0.f;
        #pragma unroll
        for (int k = 0; k < 12; ++k) a = fmaf(F.f[k], s[2*tt + k], a);
        acc[tt][ch] = a;
      }
    }
  } else {
    // edge strips: generic clamped path (4 of 2048 strips)
    #pragma unroll
    for (int tt = 0; tt < 4; ++tt) {
      const int t = t0 + tt;
      float a0=0.f, a1=0.f, a2=0.f, a3=0.f;
      for (int k = 0; k < 12; ++k) {
        int m  = 2*t + k - 5;
        int mc = m < 0 ? 0 : (m > 2*TLEN - 1 ? 2*TLEN - 1 : m);
        int tp = mc >> 1;
        int odd = mc & 1;
        float u0=0.f,u1=0.f,u2=0.f,u3=0.f;
        #pragma unroll
        for (int r = 0; r < 6; ++r) {
          int i  = odd ? (tp + r - 2) : (tp + r - 3);
          int ic = i < 0 ? 0 : (i > TLEN - 1 ? TLEN - 1 : i);
          float tap = odd ? F.f[2*r+1] : F.f[2*r];
          const float* p = xbp + (size_t)ic * CCH;
          u0 = fmaf(tap, p[0], u0); u1 = fmaf(tap, p[1], u1);
          u2 = fmaf(tap, p[2], u2); u3 = fmaf(tap, p[3], u3);
        }
        u0 *= 2.f; u1 *= 2.f; u2 *= 2.f; u3 *= 2.f;
        const float fk = F.f[k];
        a0 = fmaf(fk, snake1(u0,av[0],rv[0]), a0);
        a1 = fmaf(fk, snake1(u1,av[1],rv[1]), a1);
        a2 = fmaf(fk, snake1(u2,av[2],rv[2]), a2);
        a3 = fmaf(fk, snake1(u3,av[3],rv[3]), a3);
      }
      acc[tt][0]=a0; acc[tt][1]=a1; acc[tt][2]=a2; acc[tt][3]=a3;
    }
  }

  #pragma unroll
  for (int tt = 0; tt < 4; ++tt) {
    ushort4 o;
    o.x = f2bf(acc[tt][0]); o.y = f2bf(acc[tt][1]);
    o.z = f2bf(acc[tt][2]); o.w = f2bf(acc[tt][3]);
    *reinterpret_cast<ushort4*>(
        y + ((size_t)b * XROWS + GUARD_B + t0 + tt) * CCH + c) = o;
  }
}

// ---------------------------------------------------------------------------
// MFMA conv, 2-phase double-buffered pipeline.
// GEMM M=32768, N=512, K=1536 (3 taps x 512 ci). 128x128 tile, 4 waves.
// A staged ONCE per ci-chunk (rows t0-DIL..t0-DIL+143, 64 ci) and reused by
// all 3 taps via row-offset reads. Linear LDS dest (global_load_lds) with
// XOR-chunk swizzle applied on the global source AND the ds_read address
// (same involution both sides). B pre-packed fragment-linear.
// ---------------------------------------------------------------------------
template<int DIL>
__global__ __launch_bounds__(256)
void convm_k(const unsigned short* __restrict__ xb,
             const unsigned short* __restrict__ wp,
             const float* __restrict__ bia,
             const float* __restrict__ res,
             float* __restrict__ out) {
  __shared__ unsigned short As[2][144 * 64];   // 18KB x2
  __shared__ unsigned short Bs[2][16 * 512];   // 16KB x2  (68KB total)

  const int tid  = threadIdx.x;
  const int lane = tid & 63;
  const int wid  = tid >> 6;
  const int wr = wid >> 1, wc = wid & 1;

  // XCD-bijective swizzle: 1024 blocks, 8 XCDs -> XCD x owns 128 consecutive
  // logical blocks; logical = tb*4 + coB so the 4 co-panels sharing an
  // A-row-panel sit on the same XCD (L2 A reuse).
  const int l   = (blockIdx.x & 7) * 128 + (blockIdx.x >> 3);
  const int coB = l & 3;
  const int tb  = l >> 2;                  // 0..255
  const int b   = tb >> 6;
  const int t0  = (tb & 63) * 128;
  const int co0 = coB * 128;

  const int qq = lane >> 4;                // 0..3 (8-ci chunk within 32)
  const int r0 = lane & 15;

  // A staging lane constants: instruction i covers rows 8i..8i+7 (128B each)
  const int a_r = lane >> 3;                        // row within 8-row group
  const int a_c = (lane & 7) ^ a_r;                 // inverse-swizzled chunk
  const unsigned short* xrow0 =
      xb + ((size_t)b * XROWS + GUARD_B + t0 - DIL) * CCH;

  f32x4 acc[4][4] = {};

  auto stageA = [&](int cib, int buf) {
    #pragma unroll
    for (int u = 0; u < 5; ++u) {
      const int i = wid + u * 4;
      if (i < 18) {
        const unsigned short* g =
            xrow0 + (size_t)(8 * i + a_r) * CCH + cib * 64 + a_c * 8;
        gload16(g, &As[buf][i * 512]);
      }
    }
  };
  auto stageB = [&](int tap, int cib, int buf) {
    #pragma unroll
    for (int u = 0; u < 4; ++u) {
      const int cb = wid * 4 + u;
      const unsigned short* g =
          wp + ((((size_t)(tap * 8 + cib) * 4 + coB) * 16 + cb) * 512) + lane * 8;
      gload16(g, &Bs[buf][cb * 512]);
    }
  };
  auto compute = [&](int tap, int pa, int pb) {
    const int rowbase = tap * DIL + wr * 64 + r0;
    const int xr = (tap * DIL + r0) & 7;
    #pragma unroll
    for (int kk = 0; kk < 2; ++kk) {
      const int coff = 8 * ((kk * 4 + qq) ^ xr);
      short8 af[4], bf[4];
      #pragma unroll
      for (int i = 0; i < 4; ++i)
        af[i] = *reinterpret_cast<const short8*>(
            &As[pa][(rowbase + i * 16) * 64 + coff]);
      #pragma unroll
      for (int j = 0; j < 4; ++j)
        bf[j] = *reinterpret_cast<const short8*>(
            &Bs[pb][((wc * 4 + j) * 2 + kk) * 512 + lane * 8]);
      #pragma unroll
      for (int i = 0; i < 4; ++i)
        #pragma unroll
        for (int j = 0; j < 4; ++j)
          acc[i][j] = MFMA16(af[i], bf[j], acc[i][j]);
    }
  };

  // prologue
  stageA(0, 0);
  stageB(0, 0, 0);
  __syncthreads();                 // implicit vmcnt(0) drain

  int pa = 0, pb = 0;
  for (int cib = 0; cib < 8; ++cib) {
    #pragma unroll
    for (int tap = 0; tap < 3; ++tap) {
      // issue next stage's loads BEFORE computing (overlap under MFMA)
      if (tap < 2) {
        stageB(tap + 1, cib, pb ^ 1);
      } else if (cib < 7) {
        stageB(0, cib + 1, pb ^ 1);
        stageA(cib + 1, pa ^ 1);
      }
      compute(tap, pa, pb);
      __syncthreads();             // drains vmcnt(0): next buffers ready
      pb ^= 1;
    }
    pa ^= 1;
  }

  // epilogue: D row = qq*4 + e, col = lane&15
  #pragma unroll
  for (int j = 0; j < 4; ++j) {
    const int co = co0 + (wc * 4 + j) * 16 + r0;
    const float bv = bia[co];
    #pragma unroll
    for (int i = 0; i < 4; ++i) {
      const int t = t0 + (wr * 4 + i) * 16 + qq * 4;
      #pragma unroll
      for (int e = 0; e < 4; ++e) {
        const size_t off = ((size_t)b * TLEN + t + e) * CCH + co;
        float o = acc[i][j][e] + bv;
        if (res) o += res[off];
        out[off] = o;
      }
    }
  }
}

// ---------------------------------------------------------------------------
// host: kaiser-sinc filter (double precision, matches numpy)
// ---------------------------------------------------------------------------
static double bessel_i0(double x) {
  double t = 1.0, s = 1.0, q = x * x * 0.25;
  for (int k = 1; k < 64; ++k) {
    t *= q / ((double)k * (double)k);
    s += t;
    if (t < 1e-18 * s) break;
  }
  return s;
}

static void make_filter(Filt* F) {
  const double cutoff = 0.25, hw = 0.3;
  const int ks = 12, half = 6;
  const double A = 2.285 * (half - 1) * M_PI * (4.0 * hw) + 7.95;
  double beta;
  if (A > 50.0)       beta = 0.1102 * (A - 8.7);
  else if (A >= 21.0) beta = 0.5842 * pow(A - 21.0, 0.4) + 0.07886 * (A - 21.0);
  else                beta = 0.0;
  const double i0b = bessel_i0(beta);
  double f[12], sum = 0.0;
  for (int n = 0; n < 12; ++n) {
    double rr = 2.0 * n / (ks - 1) - 1.0;
    double w  = bessel_i0(beta * sqrt(fmax(0.0, 1.0 - rr * rr))) / i0b;
    double tm = (double)(n - half) + 0.5;
    double sx = 2.0 * cutoff * tm;
    double snc = (sx == 0.0) ? 1.0 : sin(M_PI * sx) / (M_PI * sx);
    f[n] = 2.0 * cutoff * w * snc;
    sum += f[n];
  }
  for (int n = 0; n < 12; ++n) F->f[n] = (float)(f[n] / sum);
}

// ---------------------------------------------------------------------------
extern "C" void kernel_launch(void* const* d_in, const int* in_sizes, int n_in,
                              void* d_out, int out_size, void* d_ws, size_t ws_size,
                              hipStream_t stream) {
  (void)in_sizes; (void)n_in; (void)out_size; (void)ws_size;
  const float* x  = (const float*)d_in[0];
  const float* v1 = (const float*)d_in[1];
  const float* g1 = (const float*)d_in[2];
  const float* b1 = (const float*)d_in[3];
  const float* v2 = (const float*)d_in[4];
  const float* g2 = (const float*)d_in[5];
  const float* b2 = (const float*)d_in[6];
  const float* al = (const float*)d_in[7];
  float* out = (float*)d_out;

  const size_t N = (size_t)NBATCH * TLEN * CCH;
  // ws: [w1 fp32: N][xb bf16 guarded][wp bf16 packed][scl] ~ 107 MB
  float* w1 = (float*)d_ws;
  unsigned short* xbuf = (unsigned short*)(w1 + N);
  unsigned short* wp   = xbuf + (size_t)NBATCH * XROWS * CCH;
  float* scl = (float*)(wp + (size_t)6 * 3 * CCH * CCH);

  Filt F;
  make_filter(&F);

  zguard_k<<<96, 512, 0, stream>>>(xbuf);
  scale_k<<<dim3(6, 8), 64, 0, stream>>>(v1, v2, g1, g2, scl);
  wprep_k<<<2304, 256, 0, stream>>>(v1, v2, scl, wp);

  const int cgrid = NBATCH * (TLEN / 128) * 4;          // 1024 blocks
  const int nblk_act = (NBATCH * 2048 * 128) / 256;     // 4096 blocks
  const size_t wsz = (size_t)3 * CCH * CCH;

  for (int i = 0; i < 3; ++i) {
    const float* xsrc = (i == 0) ? x : out;   // running residual lives in d_out
    // act1d #1 -> xbuf (bf16)
    act_k<<<nblk_act, 256, 0, stream>>>(xsrc, xbuf, al + (size_t)(2 * i) * CCH, F);
    // conv1 (dilated) -> w1 (fp32)
    if (i == 0)
      convm_k<1><<<cgrid, 256, 0, stream>>>(xbuf, wp + 0 * wsz, b1 + 0 * CCH, nullptr, w1);
    else if (i == 1)
      convm_k<3><<<cgrid, 256, 0, stream>>>(xbuf, wp + 1 * wsz, b1 + 1 * CCH, nullptr, w1);
    else
      convm_k<5><<<cgrid, 256, 0, stream>>>(xbuf, wp + 2 * wsz, b1 + 2 * CCH, nullptr, w1);
    // act1d #2 -> xbuf (bf16)
    act_k<<<nblk_act, 256, 0, stream>>>(w1, xbuf, al + (size_t)(2 * i + 1) * CCH, F);
    // conv2 (dil=1) + residual -> out
    convm_k<1><<<cgrid, 256, 0, stream>>>(xbuf, wp + (3 + i) * wsz, b2 + i * CCH, xsrc, out);
  }
}